// Round 1
// baseline (362.570 us; speedup 1.0000x reference)
//
#include <hip/hip_runtime.h>

#define NS 50000
#define NE 800000
#define XD 64
#define HD 64
#define YD 32

// ---------------- degree count ----------------
__global__ void k_deg(const int* __restrict__ dst, float* __restrict__ deg) {
    int e = blockIdx.x * blockDim.x + threadIdx.x;
    if (e < NE) atomicAdd(&deg[dst[e]], 1.0f);
}

__global__ void k_dinv(const float* __restrict__ deg, float* __restrict__ dinv) {
    int i = blockIdx.x * blockDim.x + threadIdx.x;
    if (i < NS) dinv[i] = rsqrtf(deg[i] + 1.0f);  // +1 = self loop
}

// ---------------- layer-1 transform: G1[s][f] = dinv[s] * sum_xf x[xf][s]*W1[xf][f]
__global__ __launch_bounds__(256) void k_xw1(const float* __restrict__ x,
                                             const float* __restrict__ W1,
                                             const float* __restrict__ dinv,
                                             float* __restrict__ G1) {
    __shared__ float w[XD * HD];
    for (int i = threadIdx.x; i < XD * HD; i += 256) w[i] = W1[i];
    __syncthreads();
    int s = blockIdx.x * 256 + threadIdx.x;
    if (s >= NS) return;
    float4 acc[HD / 4];
#pragma unroll
    for (int i = 0; i < HD / 4; ++i) acc[i] = make_float4(0.f, 0.f, 0.f, 0.f);
    for (int xf = 0; xf < XD; ++xf) {
        float xv = x[(size_t)xf * NS + s];         // coalesced over s
        const float4* wr = (const float4*)&w[xf * HD];
#pragma unroll
        for (int i = 0; i < HD / 4; ++i) {
            float4 wv = wr[i];
            acc[i].x += xv * wv.x; acc[i].y += xv * wv.y;
            acc[i].z += xv * wv.z; acc[i].w += xv * wv.w;
        }
    }
    float dv = dinv[s];
    float4* out = (float4*)&G1[(size_t)s * HD];
#pragma unroll
    for (int i = 0; i < HD / 4; ++i) {
        acc[i].x *= dv; acc[i].y *= dv; acc[i].z *= dv; acc[i].w *= dv;
        out[i] = acc[i];
    }
}

// ---------------- edge scatter: A[d][o] += G[s][o] ----------------
template <int F>
__global__ void k_scat(const int* __restrict__ src, const int* __restrict__ dst,
                       const float* __restrict__ G, float* __restrict__ A) {
    long long t = (long long)blockIdx.x * blockDim.x + threadIdx.x;
    if (t >= (long long)NE * F) return;
    int e = (int)(t >> (F == 64 ? 6 : 5));
    int o = (int)(t & (F - 1));
    int s = src[e], d = dst[e];
    atomicAdd(&A[(size_t)d * F + o], G[(size_t)s * F + o]);
}

// ---------------- epilogue-1 + layer-2 transform ----------------
// h[f] = relu(dinv*(A1+G1)+b1);  G2[s][o] = dinv * sum_f h[f]*W2[f][o]
__global__ __launch_bounds__(256) void k_l2(const float* __restrict__ A1,
                                            const float* __restrict__ G1,
                                            const float* __restrict__ b1,
                                            const float* __restrict__ W2,
                                            const float* __restrict__ dinv,
                                            float* __restrict__ G2) {
    __shared__ float w[HD * YD];
    __shared__ float bb[HD];
    for (int i = threadIdx.x; i < HD * YD; i += 256) w[i] = W2[i];
    for (int i = threadIdx.x; i < HD; i += 256) bb[i] = b1[i];
    __syncthreads();
    int s = blockIdx.x * 256 + threadIdx.x;
    if (s >= NS) return;
    float dv = dinv[s];
    float4 acc[YD / 4];
#pragma unroll
    for (int i = 0; i < YD / 4; ++i) acc[i] = make_float4(0.f, 0.f, 0.f, 0.f);
    const float4* a1 = (const float4*)&A1[(size_t)s * HD];
    const float4* g1 = (const float4*)&G1[(size_t)s * HD];
    for (int f4 = 0; f4 < HD / 4; ++f4) {
        float4 av = a1[f4], gv = g1[f4];
        float h[4];
        h[0] = fmaxf(dv * (av.x + gv.x) + bb[f4 * 4 + 0], 0.f);
        h[1] = fmaxf(dv * (av.y + gv.y) + bb[f4 * 4 + 1], 0.f);
        h[2] = fmaxf(dv * (av.z + gv.z) + bb[f4 * 4 + 2], 0.f);
        h[3] = fmaxf(dv * (av.w + gv.w) + bb[f4 * 4 + 3], 0.f);
#pragma unroll
        for (int j = 0; j < 4; ++j) {
            const float4* wr = (const float4*)&w[(f4 * 4 + j) * YD];
#pragma unroll
            for (int i = 0; i < YD / 4; ++i) {
                float4 wv = wr[i];
                acc[i].x += h[j] * wv.x; acc[i].y += h[j] * wv.y;
                acc[i].z += h[j] * wv.z; acc[i].w += h[j] * wv.w;
            }
        }
    }
    float4* out = (float4*)&G2[(size_t)s * YD];
#pragma unroll
    for (int i = 0; i < YD / 4; ++i) {
        acc[i].x *= dv; acc[i].y *= dv; acc[i].z *= dv; acc[i].w *= dv;
        out[i] = acc[i];
    }
}

// ---------------- final epilogue + transpose ----------------
__global__ void k_out(const float* __restrict__ A2, const float* __restrict__ G2,
                      const float* __restrict__ b2, const float* __restrict__ dinv,
                      float* __restrict__ out) {
    int s = blockIdx.x * blockDim.x + threadIdx.x;
    if (s >= NS) return;
    float dv = dinv[s];
#pragma unroll
    for (int o = 0; o < YD; ++o) {
        float v = dv * (A2[(size_t)s * YD + o] + G2[(size_t)s * YD + o]) + b2[o];
        out[(size_t)o * NS + s] = v;  // coalesced over s for each o
    }
}

extern "C" void kernel_launch(void* const* d_in, const int* in_sizes, int n_in,
                              void* d_out, int out_size, void* d_ws, size_t ws_size,
                              hipStream_t stream) {
    const float* x  = (const float*)d_in[0];
    const float* W1 = (const float*)d_in[1];
    const float* b1 = (const float*)d_in[2];
    const float* W2 = (const float*)d_in[3];
    const float* b2 = (const float*)d_in[4];
    const int* ei   = (const int*)d_in[5];
    const int* src = ei;
    const int* dst = ei + NE;

    float* ws = (float*)d_ws;
    // layout (floats): [deg 50k][A1 3.2M][A2 1.6M][dinv 50k][G1 3.2M][G2 1.6M]
    float* deg  = ws;
    float* A1   = ws + 50000;
    float* A2   = ws + 50000 + 3200000;
    float* dinv = ws + 50000 + 3200000 + 1600000;
    float* G1   = dinv + 50000;
    float* G2   = G1 + 3200000;
    float* out  = (float*)d_out;

    // zero deg + A1 + A2 in one contiguous async memset (graph-capturable)
    hipMemsetAsync(ws, 0, (size_t)(50000 + 3200000 + 1600000) * sizeof(float), stream);

    k_deg<<<(NE + 255) / 256, 256, 0, stream>>>(dst, deg);
    k_dinv<<<(NS + 255) / 256, 256, 0, stream>>>(deg, dinv);
    k_xw1<<<(NS + 255) / 256, 256, 0, stream>>>(x, W1, dinv, G1);
    k_scat<64><<<(NE * 64) / 256, 256, 0, stream>>>(src, dst, G1, A1);
    k_l2<<<(NS + 255) / 256, 256, 0, stream>>>(A1, G1, b1, W2, dinv, G2);
    k_scat<32><<<(NE * 32) / 256, 256, 0, stream>>>(src, dst, G2, A2);
    k_out<<<(NS + 255) / 256, 256, 0, stream>>>(A2, G2, b2, dinv, out);
}